// Round 7
// baseline (309.076 us; speedup 1.0000x reference)
//
#include <hip/hip_runtime.h>

// Biquad DF2T over [B=512, T=48000] fp32, per-channel coeffs.
// One block per channel, 512 threads, 6 stages of 8000 samples.
// x is DMA'd global->LDS via global_load_lds (NO VGPR staging: removes the
// spill failure mode of rounds 1/6); barriers are raw s_barrier with
// lgkmcnt-only waits and NO "memory" clobber (removes the vmcnt-drain
// failure mode of rounds 0/2/3); DMA completion is enforced by hand-counted
// s_waitcnt vmcnt(N) in the m201 discipline:
//   per wave per stage: 4 global_load_lds (1KB each) + 4 global_store_dwordx4
//   steady-state wait = vmcnt(8)  (= 4 next-stage DMAs + 4 prev stores
//   allowed to remain in flight; never drained mid-kernel).
// LDS row reads: row = 16 samples = 4 granules; source-side XOR swizzle
// (slot = g ^ ((g>>3)&3), LDS dest linear per guide rule 21) makes the
// strided ds_read_b128 2-way bank-aliased (free) instead of 8-way.
// y rows are exactly one aligned 64B line each -> direct nontemporal
// stores, no LDS transpose, no writeback phase.

#define B_CH   512
#define T_LEN  48000
#define NSTAGE 6
#define SSAMP  8000         // samples per stage
#define SGRAN  2000         // 16B granules per stage
#define NACT   500          // active compute threads
#define L      16           // samples per thread per stage (one 64B line)
#define NWAVE  8
#define BUFG   2048         // granules per LDS buffer (padded to 512*4)

typedef float f4_t __attribute__((ext_vector_type(4)));

#define SCHED_FENCE() __builtin_amdgcn_sched_barrier(0)

// counted vmcnt wait; N = #vmem instrs issued after the group we await
#define WAIT_VM(N) do { SCHED_FENCE();                       \
    asm volatile("s_waitcnt vmcnt(" #N ")");                 \
    SCHED_FENCE(); } while (0)

// raw barrier: drain LDS ops only; vmcnt (DMA + stores) stays in flight
__device__ __forceinline__ void barrier_nodrain()
{
    SCHED_FENCE();
    asm volatile("s_waitcnt lgkmcnt(0)");
    __builtin_amdgcn_s_barrier();
    SCHED_FENCE();
}

// async 16B global->LDS (zero VGPR staging). lds dest is wave-uniform;
// HW writes lane l at dst + l*16.
__device__ __forceinline__ void load_lds16(const float* g, f4_t* l)
{
    __builtin_amdgcn_global_load_lds(
        (const __attribute__((address_space(1))) unsigned*)g,
        (__attribute__((address_space(3))) unsigned*)l, 16, 0, 0);
}

// G = A^L, A = [[-a1,1],[-a2,0]] (binary exponentiation)
__device__ __forceinline__ void mat_pow(float A1, float A2,
                                        float& G00, float& G01,
                                        float& G10, float& G11)
{
    float m00 = -A1, m01 = 1.f, m10 = -A2, m11 = 0.f;
    float f00 = 1.f, f01 = 0.f, f10 = 0.f, f11 = 1.f;
    int e = L;
    while (e) {
        if (e & 1) {
            const float t00 = f00*m00 + f01*m10, t01 = f00*m01 + f01*m11;
            const float t10 = f10*m00 + f11*m10, t11 = f10*m01 + f11*m11;
            f00 = t00; f01 = t01; f10 = t10; f11 = t11;
        }
        e >>= 1;
        if (!e) break;
        const float s00 = m00*m00 + m01*m10, s01 = m00*m01 + m01*m11;
        const float s10 = m10*m00 + m11*m10, s11 = m10*m01 + m11*m11;
        m00 = s00; m01 = s01; m10 = s10; m11 = s11;
    }
    G00 = f00; G01 = f01; G10 = f10; G11 = f11;
}

__global__ __launch_bounds__(512, 4) void k_biquad_dma(
    const float* __restrict__ x,
    const float* __restrict__ b0v, const float* __restrict__ b1v,
    const float* __restrict__ b2v,
    const float* __restrict__ a1v, const float* __restrict__ a2v,
    float* __restrict__ y)
{
    __shared__ f4_t bufA[BUFG];             // 32 KB
    __shared__ f4_t bufB[BUFG];             // 32 KB
    __shared__ volatile float aggP[NSTAGE][NWAVE][4];
    __shared__ volatile float aggW[NSTAGE][NWAVE][2];

    const int b    = blockIdx.x;
    const int t    = threadIdx.x;
    const int lane = t & 63;
    const int wid  = t >> 6;

    const float A1 = a1v[b], A2 = a2v[b];
    const float B0 = b0v[b], B1 = b1v[b], B2 = b2v[b];
    // y-eliminated state form: z1' = c1*x - a1*z1 + z2 ; z2' = c2*x - a2*z1
    const float c1 = B1 - A1 * B0;
    const float c2 = B2 - A2 * B0;

    float G00, G01, G10, G11;
    mat_pow(A1, A2, G00, G01, G10, G11);

    const float* __restrict__ xb = x + (size_t)b * T_LEN;
    float*       __restrict__ yb = y + (size_t)b * T_LEN;

    float cz1 = 0.f, cz2 = 0.f;   // inter-stage carry state

    // issue this wave's 4 DMA instrs for one stage (source-side swizzle,
    // linear LDS dest). Slots >= SGRAN are padding, clamped, never read.
    auto issue_dma = [&](const float* xs, f4_t* buf) {
        SCHED_FENCE();
        #pragma unroll
        for (int j = 0; j < 4; ++j) {
            const int sb = (wid * 4 + j) * 64;   // wave-uniform slot base
            const int sl = sb + lane;            // per-lane slot
            int g = sl ^ ((sl >> 3) & 3);        // swizzled source granule
            if (g >= SGRAN) g = 0;               // clamp padding (unread)
            load_lds16(xs + g * 4, buf + sb);
        }
        SCHED_FENCE();
    };

    auto body = [&](int s, const f4_t* buf) {
        barrier_nodrain();   // own DMA awaited via WAIT_VM; sync all waves

        // ---- row read: 4 x ds_read_b128, swizzled (2-way alias, free)
        f4_t xr[4];
        if (t < NACT) {
            #pragma unroll
            for (int k = 0; k < 4; ++k) {
                const int slot = 4 * t + (k ^ ((t >> 1) & 3));
                xr[k] = buf[slot];
            }
        }

        // ---- local zero-state response (y-eliminated form)
        float P00, P01, P10, P11, w0, w1;
        if (t < NACT) {
            float z1 = 0.f, z2 = 0.f;
            #pragma unroll
            for (int k = 0; k < 4; ++k) {
                const f4_t v = xr[k];
                { const float xn = v.x; const float n1 = c1*xn + z2 - A1*z1; z2 = c2*xn - A2*z1; z1 = n1; }
                { const float xn = v.y; const float n1 = c1*xn + z2 - A1*z1; z2 = c2*xn - A2*z1; z1 = n1; }
                { const float xn = v.z; const float n1 = c1*xn + z2 - A1*z1; z2 = c2*xn - A2*z1; z1 = n1; }
                { const float xn = v.w; const float n1 = c1*xn + z2 - A1*z1; z2 = c2*xn - A2*z1; z1 = n1; }
            }
            P00 = G00; P01 = G01; P10 = G10; P11 = G11; w0 = z1; w1 = z2;
        } else {
            P00 = 1.f; P01 = 0.f; P10 = 0.f; P11 = 1.f; w0 = 0.f; w1 = 0.f;
        }

        // ---- intra-wave inclusive Kogge-Stone via shuffles (no barriers)
        #pragma unroll
        for (int off = 1; off < 64; off <<= 1) {
            const float e00 = __shfl_up(P00, off);
            const float e01 = __shfl_up(P01, off);
            const float e10 = __shfl_up(P10, off);
            const float e11 = __shfl_up(P11, off);
            const float u0  = __shfl_up(w0,  off);
            const float u1  = __shfl_up(w1,  off);
            if (lane >= off) {
                const float n00 = P00*e00 + P01*e10, n01 = P00*e01 + P01*e11;
                const float n10 = P10*e00 + P11*e10, n11 = P10*e01 + P11*e11;
                w0 = P00*u0 + P01*u1 + w0;
                w1 = P10*u0 + P11*u1 + w1;
                P00 = n00; P01 = n01; P10 = n10; P11 = n11;
            }
        }

        // publish wave aggregates (lane 63 inclusive = whole-wave transform)
        if (lane == 63) {
            aggP[s][wid][0] = P00; aggP[s][wid][1] = P01;
            aggP[s][wid][2] = P10; aggP[s][wid][3] = P11;
            aggW[s][wid][0] = w0;  aggW[s][wid][1] = w1;
        }

        // exclusive-within-wave = inclusive shifted down one lane
        float E00 = __shfl_up(P00, 1), E01 = __shfl_up(P01, 1);
        float E10 = __shfl_up(P10, 1), E11 = __shfl_up(P11, 1);
        float Ew0 = __shfl_up(w0, 1),  Ew1 = __shfl_up(w1, 1);
        if (lane == 0) { E00 = 1.f; E01 = 0.f; E10 = 0.f; E11 = 1.f; Ew0 = 0.f; Ew1 = 0.f; }

        barrier_nodrain();   // aggregates visible

        // ---- carry-aware fold of wave aggregates (wave-uniform)
        float s0 = cz1, s1 = cz2, my0 = cz1, my1 = cz2;
        #pragma unroll
        for (int k = 0; k < NWAVE; ++k) {
            if (k == wid) { my0 = s0; my1 = s1; }
            const float p0 = aggP[s][k][0], p1 = aggP[s][k][1];
            const float p2 = aggP[s][k][2], p3 = aggP[s][k][3];
            const float q0 = aggW[s][k][0], q1 = aggW[s][k][1];
            const float n0 = p0*s0 + p1*s1 + q0;
            const float n1 = p2*s0 + p3*s1 + q1;
            s0 = n0; s1 = n1;
        }
        cz1 = s0; cz2 = s1;   // carry advanced past this stage

        // this thread's true initial state
        float z1 = E00*my0 + E01*my1 + Ew0;
        float z2 = E10*my0 + E11*my1 + Ew1;

        // ---- replay exact reference arithmetic; row = one aligned 64B
        //      line -> direct nontemporal stores (4 instrs), fire & forget
        if (t < NACT) {
            f4_t* q = (f4_t*)(yb + s * SSAMP + t * L);
            #pragma unroll
            for (int k = 0; k < 4; ++k) {
                const f4_t v = xr[k];
                f4_t o;
                { const float xn = v.x; const float yn = B0*xn + z1; o.x = yn;
                  const float n1 = B1*xn - A1*yn + z2; z2 = B2*xn - A2*yn; z1 = n1; }
                { const float xn = v.y; const float yn = B0*xn + z1; o.y = yn;
                  const float n1 = B1*xn - A1*yn + z2; z2 = B2*xn - A2*yn; z1 = n1; }
                { const float xn = v.z; const float yn = B0*xn + z1; o.z = yn;
                  const float n1 = B1*xn - A1*yn + z2; z2 = B2*xn - A2*yn; z1 = n1; }
                { const float xn = v.w; const float yn = B0*xn + z1; o.w = yn;
                  const float n1 = B1*xn - A1*yn + z2; z2 = B2*xn - A2*yn; z1 = n1; }
                __builtin_nontemporal_store(o, q + k);
            }
        }
        SCHED_FENCE();   // pin stores before the next stage's DMA issue
    };

    // ---- pipeline: DMA(s+1) -> counted wait for DMA(s) -> body(s)
    // vmcnt accounting (per wave, in-order): 4 DMAs + 4 stores per stage.
    issue_dma(xb + 0 * SSAMP, bufA);
    issue_dma(xb + 1 * SSAMP, bufB);  WAIT_VM(4);  body(0, bufA);
    issue_dma(xb + 2 * SSAMP, bufA);  WAIT_VM(8);  body(1, bufB);
    issue_dma(xb + 3 * SSAMP, bufB);  WAIT_VM(8);  body(2, bufA);
    issue_dma(xb + 4 * SSAMP, bufA);  WAIT_VM(8);  body(3, bufB);
    issue_dma(xb + 5 * SSAMP, bufB);  WAIT_VM(8);  body(4, bufA);
                                      WAIT_VM(4);  body(5, bufB);
}

extern "C" void kernel_launch(void* const* d_in, const int* in_sizes, int n_in,
                              void* d_out, int out_size, void* d_ws, size_t ws_size,
                              hipStream_t stream) {
    const float* x  = (const float*)d_in[0];
    const float* b0 = (const float*)d_in[1];
    const float* b1 = (const float*)d_in[2];
    const float* b2 = (const float*)d_in[3];
    const float* a1 = (const float*)d_in[4];
    const float* a2 = (const float*)d_in[5];
    float* y = (float*)d_out;

    k_biquad_dma<<<dim3(B_CH), dim3(512), 0, stream>>>(x, b0, b1, b2, a1, a2, y);
}

// Round 8
// 190.434 us; speedup vs baseline: 1.6230x; 1.6230x over previous
//
#include <hip/hip_runtime.h>

// Biquad DF2T over [B=512, T=48000] fp32, per-channel coeffs.
// One block per channel, 512 threads, 6 stages of 8000 samples.
// Round-8 structure: minimize LDS-pipe work + wave-private data path.
//  - x: global_load_lds DMA, double-buffered, counted WAIT_VM (never drain)
//  - scan: w-ONLY Kogge-Stone (12 bpermutes, was 42): the self-segment
//    transform at round j is exactly G^(2^j*L) for every updating lane
//    (lane-invariant) -> precomputed by squaring. Per-thread exclusive
//    transform E = G^(lane*L) via 6 static selects, computed ONCE.
//  - wave aggregates: only w (2 floats); wave transform = G^(64L) const
//    (G^(52L) for the 52-thread tail wave).
//  - ONE barrier per stage (aggregate exchange). x/y LDS is wave-private:
//    wave w DMAs, reads, replays into, and writes back slots [256w,256w+256).
//  - y transpose reuses the consumed x buffer (no extra LDS); writeback is
//    coalesced 1KB/wave-instr -> nontemporal is safe (round 7 lesson: nt on
//    scattered 16B stores caused 2.6x write amplification; nt only on
//    full-line coalesced stores).
//  - bank swizzle slot = g ^ ((g>>3)&3) applied on DMA source AND reads
//    (involution, both-sides rule).

#define B_CH   512
#define T_LEN  48000
#define NSTAGE 6
#define SSAMP  8000         // samples per stage
#define SGRAN  2000         // 16B granules per stage
#define NACT   500          // active compute threads
#define L      16           // samples per thread per stage
#define NWAVE  8
#define BUFG   2048         // granules per LDS buffer (32 KB)

typedef float f4_t __attribute__((ext_vector_type(4)));

#define SCHED_FENCE() __builtin_amdgcn_sched_barrier(0)

#define WAIT_VM(N) do { SCHED_FENCE();                       \
    asm volatile("s_waitcnt vmcnt(" #N ")");                 \
    SCHED_FENCE(); } while (0)

// raw barrier: drain LDS ops only; vmcnt (DMA + stores) stays in flight
__device__ __forceinline__ void barrier_nodrain()
{
    SCHED_FENCE();
    asm volatile("s_waitcnt lgkmcnt(0)");
    __builtin_amdgcn_s_barrier();
    SCHED_FENCE();
}

__device__ __forceinline__ void load_lds16(const float* g, f4_t* l)
{
    __builtin_amdgcn_global_load_lds(
        (const __attribute__((address_space(1))) unsigned*)g,
        (__attribute__((address_space(3))) unsigned*)l, 16, 0, 0);
}

__device__ __forceinline__ int swz(int g) { return g ^ ((g >> 3) & 3); }

// 2x2 matrix multiply: R = X * Y
#define MATMUL(R00,R01,R10,R11, X00,X01,X10,X11, Y00,Y01,Y10,Y11) do { \
    const float t00 = X00*Y00 + X01*Y10, t01 = X00*Y01 + X01*Y11;      \
    const float t10 = X10*Y00 + X11*Y10, t11 = X10*Y01 + X11*Y11;      \
    R00 = t00; R01 = t01; R10 = t10; R11 = t11; } while (0)

__global__ __launch_bounds__(512, 4) void k_biquad_v8(
    const float* __restrict__ x,
    const float* __restrict__ b0v, const float* __restrict__ b1v,
    const float* __restrict__ b2v,
    const float* __restrict__ a1v, const float* __restrict__ a2v,
    float* __restrict__ y)
{
    __shared__ f4_t bufA[BUFG];                      // 32 KB
    __shared__ f4_t bufB[BUFG];                      // 32 KB
    __shared__ volatile float aggW[NSTAGE][NWAVE][2];

    const int b    = blockIdx.x;
    const int t    = threadIdx.x;
    const int lane = t & 63;
    const int wid  = t >> 6;

    const float A1 = a1v[b], A2 = a2v[b];
    const float B0 = b0v[b], B1 = b1v[b], B2 = b2v[b];
    // y-eliminated state form: z1' = c1*x - a1*z1 + z2 ; z2' = c2*x - a2*z1
    const float c1 = B1 - A1 * B0;
    const float c2 = B2 - A2 * B0;

    // ---- one-time transform constants (loop-invariant) ----
    // G = A^L, A = [[-a1,1],[-a2,0]]; L = 16 -> 4 squarings of A.
    float G00 = -A1, G01 = 1.f, G10 = -A2, G11 = 0.f;
    MATMUL(G00,G01,G10,G11, G00,G01,G10,G11, G00,G01,G10,G11);   // A^2
    MATMUL(G00,G01,G10,G11, G00,G01,G10,G11, G00,G01,G10,G11);   // A^4
    MATMUL(G00,G01,G10,G11, G00,G01,G10,G11, G00,G01,G10,G11);   // A^8
    MATMUL(G00,G01,G10,G11, G00,G01,G10,G11, G00,G01,G10,G11);   // A^16 = G

    // Gp[j] = G^(2^j), j = 0..6 (Gp[6] = G^64 = full-wave transform)
    float Gp[7][4];
    Gp[0][0]=G00; Gp[0][1]=G01; Gp[0][2]=G10; Gp[0][3]=G11;
    #pragma unroll
    for (int j = 1; j < 7; ++j) {
        MATMUL(Gp[j][0],Gp[j][1],Gp[j][2],Gp[j][3],
               Gp[j-1][0],Gp[j-1][1],Gp[j-1][2],Gp[j-1][3],
               Gp[j-1][0],Gp[j-1][1],Gp[j-1][2],Gp[j-1][3]);
    }
    // E = G^lane (binary expo over lane bits; powers of G commute)
    float E00 = 1.f, E01 = 0.f, E10 = 0.f, E11 = 1.f;
    #pragma unroll
    for (int j = 0; j < 6; ++j) {
        float n00, n01, n10, n11;
        MATMUL(n00,n01,n10,n11, Gp[j][0],Gp[j][1],Gp[j][2],Gp[j][3],
               E00,E01,E10,E11);
        const bool sel = (lane >> j) & 1;
        E00 = sel ? n00 : E00; E01 = sel ? n01 : E01;
        E10 = sel ? n10 : E10; E11 = sel ? n11 : E11;
    }
    // g52 = G^52 = G^32 * G^16 * G^4 (tail wave covers 52 threads)
    float g52_00, g52_01, g52_10, g52_11;
    MATMUL(g52_00,g52_01,g52_10,g52_11,
           Gp[5][0],Gp[5][1],Gp[5][2],Gp[5][3],
           Gp[4][0],Gp[4][1],Gp[4][2],Gp[4][3]);
    MATMUL(g52_00,g52_01,g52_10,g52_11,
           g52_00,g52_01,g52_10,g52_11,
           Gp[2][0],Gp[2][1],Gp[2][2],Gp[2][3]);

    const float* __restrict__ xb = x + (size_t)b * T_LEN;
    float*       __restrict__ yb = y + (size_t)b * T_LEN;

    float cz1 = 0.f, cz2 = 0.f;   // inter-stage carry state

    // wave-private DMA: wave w fills slots [256w, 256w+256) of buf
    auto issue_dma = [&](const float* xs, f4_t* buf) {
        SCHED_FENCE();
        #pragma unroll
        for (int j = 0; j < 4; ++j) {
            const int sb = 256 * wid + 64 * j;   // wave-uniform slot base
            int g = swz(sb + lane);              // logical granule for slot
            if (g >= SGRAN) g = 0;               // padding slots (unread)
            load_lds16(xs + g * 4, buf + sb);
        }
        SCHED_FENCE();
    };

    auto body = [&](int s, f4_t* buf, const float* nxt_src) {
        // ---- xr: own row, swizzled slots (phys 4t+(k^x) holds granule 4t+k)
        const int xk = (t >> 1) & 3;
        f4_t xr[4];
        if (t < NACT) {
            #pragma unroll
            for (int k = 0; k < 4; ++k) xr[k] = buf[4 * t + (k ^ xk)];
        }

        // ---- local zero-state response (y-eliminated form)
        float w0, w1;
        {
            float z1 = 0.f, z2 = 0.f;
            if (t < NACT) {
                #pragma unroll
                for (int k = 0; k < 4; ++k) {
                    const f4_t v = xr[k];
                    { const float xn = v.x; const float n1 = c1*xn + z2 - A1*z1; z2 = c2*xn - A2*z1; z1 = n1; }
                    { const float xn = v.y; const float n1 = c1*xn + z2 - A1*z1; z2 = c2*xn - A2*z1; z1 = n1; }
                    { const float xn = v.z; const float n1 = c1*xn + z2 - A1*z1; z2 = c2*xn - A2*z1; z1 = n1; }
                    { const float xn = v.w; const float n1 = c1*xn + z2 - A1*z1; z2 = c2*xn - A2*z1; z1 = n1; }
                }
            }
            w0 = z1; w1 = z2;
        }

        // ---- w-only Kogge-Stone: self transform at round j is G^(2^j)
        #pragma unroll
        for (int j = 0; j < 6; ++j) {
            const int off = 1 << j;
            const float u0 = __shfl_up(w0, off);
            const float u1 = __shfl_up(w1, off);
            if (lane >= off) {
                w0 = Gp[j][0]*u0 + Gp[j][1]*u1 + w0;
                w1 = Gp[j][2]*u0 + Gp[j][3]*u1 + w1;
            }
        }
        // exclusive w = inclusive shifted down one lane
        float ex0 = __shfl_up(w0, 1), ex1 = __shfl_up(w1, 1);
        if (lane == 0) { ex0 = 0.f; ex1 = 0.f; }

        // publish wave-aggregate w (last ACTIVE lane: 51 in tail wave)
        if (lane == ((wid == 7) ? 51 : 63)) {
            aggW[s][wid][0] = w0; aggW[s][wid][1] = w1;
        }

        barrier_nodrain();   // the ONLY barrier in the stage

        // ---- fold: entry state per wave; wave transform = G^64 (g52 tail)
        float s0 = cz1, s1 = cz2, my0 = cz1, my1 = cz2;
        #pragma unroll
        for (int k = 0; k < NWAVE; ++k) {
            if (k == wid) { my0 = s0; my1 = s1; }
            const float q0 = aggW[s][k][0], q1 = aggW[s][k][1];
            float n0, n1;
            if (k < 7) {
                n0 = Gp[6][0]*s0 + Gp[6][1]*s1 + q0;
                n1 = Gp[6][2]*s0 + Gp[6][3]*s1 + q1;
            } else {
                n0 = g52_00*s0 + g52_01*s1 + q0;
                n1 = g52_10*s0 + g52_11*s1 + q1;
            }
            s0 = n0; s1 = n1;
        }
        cz1 = s0; cz2 = s1;   // carry advanced past this stage

        // this thread's true initial state: E * wave_entry + exclusive w
        float z1 = E00*my0 + E01*my1 + ex0;
        float z2 = E10*my0 + E11*my1 + ex1;

        // ---- replay exact reference arithmetic; y overwrites own x slots
        if (t < NACT) {
            #pragma unroll
            for (int k = 0; k < 4; ++k) {
                const f4_t v = xr[k];
                f4_t o;
                { const float xn = v.x; const float yn = B0*xn + z1; o.x = yn;
                  const float n1 = B1*xn - A1*yn + z2; z2 = B2*xn - A2*yn; z1 = n1; }
                { const float xn = v.y; const float yn = B0*xn + z1; o.y = yn;
                  const float n1 = B1*xn - A1*yn + z2; z2 = B2*xn - A2*yn; z1 = n1; }
                { const float xn = v.z; const float yn = B0*xn + z1; o.z = yn;
                  const float n1 = B1*xn - A1*yn + z2; z2 = B2*xn - A2*yn; z1 = n1; }
                { const float xn = v.w; const float yn = B0*xn + z1; o.w = yn;
                  const float n1 = B1*xn - A1*yn + z2; z2 = B2*xn - A2*yn; z1 = n1; }
                buf[4 * t + (k ^ xk)] = o;
            }
        }

        // ---- writeback: own region, coalesced 1KB/wave-instr, nt-safe.
        //      Same-wave DS ordering makes read-after-write safe; no barrier.
        f4_t* ysg = (f4_t*)(yb + s * SSAMP);
        #pragma unroll
        for (int j = 0; j < 4; ++j) {
            const int l = 256 * wid + 64 * j + lane;   // logical granule
            if (l < SGRAN) {
                const f4_t v = buf[swz(l)];
                __builtin_nontemporal_store(v, ysg + l);
            }
        }

        // ---- issue DMA for stage s+2 into own (now-dead) region
        if (nxt_src) issue_dma(nxt_src, buf);
    };

    // ---- pipeline: per wave per stage = 4 stores + 4 DMA; in-order vmcnt
    // retirement => WAIT_VM(8) retires this stage's DMA while keeping the
    // previous stores + next DMA in flight. Never drains to 0 mid-kernel.
    issue_dma(xb + 0 * SSAMP, bufA);
    issue_dma(xb + 1 * SSAMP, bufB);
    WAIT_VM(4); body(0, bufA, xb + 2 * SSAMP);
    WAIT_VM(8); body(1, bufB, xb + 3 * SSAMP);
    WAIT_VM(8); body(2, bufA, xb + 4 * SSAMP);
    WAIT_VM(8); body(3, bufB, xb + 5 * SSAMP);
    WAIT_VM(8); body(4, bufA, nullptr);
    WAIT_VM(4); body(5, bufB, nullptr);
}

extern "C" void kernel_launch(void* const* d_in, const int* in_sizes, int n_in,
                              void* d_out, int out_size, void* d_ws, size_t ws_size,
                              hipStream_t stream) {
    const float* x  = (const float*)d_in[0];
    const float* b0 = (const float*)d_in[1];
    const float* b1 = (const float*)d_in[2];
    const float* b2 = (const float*)d_in[3];
    const float* a1 = (const float*)d_in[4];
    const float* a2 = (const float*)d_in[5];
    float* y = (float*)d_out;

    k_biquad_v8<<<dim3(B_CH), dim3(512), 0, stream>>>(x, b0, b1, b2, a1, a2, y);
}